// Round 5
// baseline (131.070 us; speedup 1.0000x reference)
//
#include <hip/hip_runtime.h>
#include <hip/hip_bf16.h>
#include <stdint.h>

using bf = __bf16;
typedef __attribute__((ext_vector_type(8))) __bf16 bf16x8;
typedef __attribute__((ext_vector_type(4))) float f32x4;

#define M_TOT 4096
#define D_EMB 512
#define F_FFN 2048

// ---------- async global->LDS, 16B per lane ----------
__device__ __forceinline__ void gload_lds16(const void* g, void* l) {
  __builtin_amdgcn_global_load_lds(
      (const __attribute__((address_space(1))) uint32_t*)g,
      (__attribute__((address_space(3))) uint32_t*)l, 16, 0, 0);
}

// ---------- 128B-row swizzled tiles ----------
__device__ __forceinline__ int swz128(int row, int b) {
  return row * 128 + (b ^ ((row & 7) << 4));
}
__device__ __forceinline__ bf16x8 ldf128(const char* base, int row, int b) {
  return *(const bf16x8*)(base + swz128(row, b));
}
// linear LDS dest + inverse-swizzled global source chunk (rule #21)
template <int ROWS>
__device__ __forceinline__ void stage_tile(const bf* gsrc, int ld, char* lbase, int wave, int lane) {
  const int rsub = lane >> 3, csub = lane & 7;
#pragma unroll
  for (int i = 0; i < ROWS / 32; ++i) {
    int chunk = wave + i * 4;
    int row = chunk * 8 + rsub;
    int sc = csub ^ (row & 7);
    gload_lds16((const char*)gsrc + (size_t)row * (size_t)(ld * 2) + sc * 16, lbase + chunk * 1024);
  }
}

// ---------- prep: phi features (rank-16 factorization of the gram) ----------
__global__ __launch_bounds__(256) void k_phi(const float* __restrict__ x, bf* __restrict__ phib) {
  int i = blockIdx.x * 256 + threadIdx.x;
  float c[4], s[4];
#pragma unroll
  for (int k = 0; k < 4; ++k) {
    float f = x[(size_t)i * D_EMB + k] * 0.5f;
    sincosf(f, &s[k], &c[k]);
  }
#pragma unroll
  for (int m = 0; m < 16; ++m) {
    float p = 1.0f;
#pragma unroll
    for (int k = 0; k < 4; ++k) p *= ((m >> k) & 1) ? s[k] : c[k];
    phib[(size_t)i * 32 + m] = (bf)p;
  }
#pragma unroll
  for (int m = 16; m < 32; ++m) phib[(size_t)i * 32 + m] = (bf)0.0f;
}

// ---------- prep: transpose + cvt; PERM applies the k-slot column permutation ----------
// p(j) = (j&~31) | ((j>>2)&3)<<3 | ((j>>4)&1)<<2 | (j&3)
template <bool PERM>
__global__ __launch_bounds__(256) void k_transpose_cvt(const float* __restrict__ in,
                                                       bf* __restrict__ out, int R, int C) {
  __shared__ float tile[32][33];
  int c0 = blockIdx.x * 32, r0 = blockIdx.y * 32;
  int tx = threadIdx.x, ty = threadIdx.y;
#pragma unroll
  for (int i = 0; i < 32; i += 8)
    tile[ty + i][tx] = in[(size_t)(r0 + ty + i) * C + c0 + tx];
  __syncthreads();
#pragma unroll
  for (int i = 0; i < 32; i += 8) {
    int j = r0 + tx;
    int col = PERM ? ((j & ~31) | (((j >> 2) & 3) << 3) | (((j >> 4) & 1) << 2) | (j & 3)) : j;
    out[(size_t)(c0 + ty + i) * R + col] = (bf)tile[tx][ty + i];
  }
}

// ---------- fused: out = |Phi Phi^T| @ flat, S fully register-resident ----------
// S^T-MFMA: mfma(A=phiJ, B=phiI) -> lane(lr,lg) holds S[m=lr][j=4lg+r].
// Two 16-j tiles -> K=32 A-frag [tile0|tile1]; B (flatTp) column-permuted to match.
// Block 32m x 64d, 4 waves (wm,wd), wave 16m x 32d. Grid 1024 -> 4 blocks/CU.
__global__ __launch_bounds__(256, 4) void k_gram(const bf* __restrict__ phib,
                                                 const bf* __restrict__ flatTp,
                                                 bf* __restrict__ outb) {
  __shared__ __align__(16) char sm[3 * 8192];  // 3 x [64 d][64 j] bf16, swz128
  const int tid = threadIdx.x;
  const int wave = tid >> 6, lane = tid & 63;
  const int lr = lane & 15, lg = lane >> 4;
  const int wm = wave & 1, wd = wave >> 1;
  const int lin = blockIdx.x;
  const int n0 = (lin & 7) * 64;   // d-slab: one per XCD (round-robin dispatch)
  const int m0 = (lin >> 3) * 32;

  // loop-invariant phiI fragment: phi[m0 + wm*16 + lr][8lg..8lg+7]
  const bf16x8 aphi = *(const bf16x8*)(phib + (size_t)(m0 + wm * 16 + lr) * 32 + lg * 8);
  // phiJ fragments for iter 0 (tiles 0..3)
  bf16x8 cur0 = *(const bf16x8*)(phib + (size_t)(0 * 16 + lr) * 32 + lg * 8);
  bf16x8 cur1 = *(const bf16x8*)(phib + (size_t)(1 * 16 + lr) * 32 + lg * 8);
  bf16x8 cur2 = *(const bf16x8*)(phib + (size_t)(2 * 16 + lr) * 32 + lg * 8);
  bf16x8 cur3 = *(const bf16x8*)(phib + (size_t)(3 * 16 + lr) * 32 + lg * 8);
  // stage ft[0], ft[1]
  stage_tile<64>(flatTp + (size_t)n0 * M_TOT, M_TOT, sm, wave, lane);
  stage_tile<64>(flatTp + (size_t)n0 * M_TOT + 64, M_TOT, sm + 8192, wave, lane);

  f32x4 acc0 = {0.f, 0.f, 0.f, 0.f}, acc1 = acc0;

  constexpr int NT = M_TOT / 64;  // 64
  for (int t = 0; t < NT; ++t) {
    char* ftc = sm + (t % 3) * 8192;
    // exact counted waits: #VMEM issued after ft[t]'s stage:
    // t=0: ft[1](8); steady: phiJ(t)(4)+ft[t+1](8)=12; tail: phiJ(NT-1)(4)
    if (t == 0)          asm volatile("s_waitcnt vmcnt(8)" ::: "memory");
    else if (t + 1 < NT) asm volatile("s_waitcnt vmcnt(12)" ::: "memory");
    else                 asm volatile("s_waitcnt vmcnt(4)" ::: "memory");
    __builtin_amdgcn_s_barrier();

    // prefetch next iter's phiJ fragments (VMEM, issued before stage)
    bf16x8 nxt0, nxt1, nxt2, nxt3;
    if (t + 1 < NT) {
      const bf* pb = phib + (size_t)(t + 1) * 64 * 32;
      nxt0 = *(const bf16x8*)(pb + (size_t)(0 * 16 + lr) * 32 + lg * 8);
      nxt1 = *(const bf16x8*)(pb + (size_t)(1 * 16 + lr) * 32 + lg * 8);
      nxt2 = *(const bf16x8*)(pb + (size_t)(2 * 16 + lr) * 32 + lg * 8);
      nxt3 = *(const bf16x8*)(pb + (size_t)(3 * 16 + lr) * 32 + lg * 8);
    }
    // stage ft[t+2]
    if (t + 2 < NT)
      stage_tile<64>(flatTp + (size_t)n0 * M_TOT + (t + 2) * 64, M_TOT,
                     sm + ((t + 2) % 3) * 8192, wave, lane);

    // S^T MFMAs (K=32, phi padded) -> in-register A-fragments
    f32x4 sv0 = __builtin_amdgcn_mfma_f32_16x16x32_bf16(cur0, aphi, f32x4{0.f,0.f,0.f,0.f}, 0, 0, 0);
    f32x4 sv1 = __builtin_amdgcn_mfma_f32_16x16x32_bf16(cur1, aphi, f32x4{0.f,0.f,0.f,0.f}, 0, 0, 0);
    f32x4 sv2 = __builtin_amdgcn_mfma_f32_16x16x32_bf16(cur2, aphi, f32x4{0.f,0.f,0.f,0.f}, 0, 0, 0);
    f32x4 sv3 = __builtin_amdgcn_mfma_f32_16x16x32_bf16(cur3, aphi, f32x4{0.f,0.f,0.f,0.f}, 0, 0, 0);
    bf16x8 af0, af1;
#pragma unroll
    for (int o = 0; o < 4; ++o) {
      af0[o]     = (bf)fabsf(sv0[o]);
      af0[4 + o] = (bf)fabsf(sv1[o]);
      af1[o]     = (bf)fabsf(sv2[o]);
      af1[4 + o] = (bf)fabsf(sv3[o]);
    }
    // main MFMAs: acc[f] over d-frags, K=32 per window, 2 windows
    {
      bf16x8 b00 = ldf128(ftc, wd * 32 + lr,      0 * 64 + lg * 16);
      bf16x8 b01 = ldf128(ftc, wd * 32 + 16 + lr, 0 * 64 + lg * 16);
      acc0 = __builtin_amdgcn_mfma_f32_16x16x32_bf16(af0, b00, acc0, 0, 0, 0);
      acc1 = __builtin_amdgcn_mfma_f32_16x16x32_bf16(af0, b01, acc1, 0, 0, 0);
      bf16x8 b10 = ldf128(ftc, wd * 32 + lr,      1 * 64 + lg * 16);
      bf16x8 b11 = ldf128(ftc, wd * 32 + 16 + lr, 1 * 64 + lg * 16);
      acc0 = __builtin_amdgcn_mfma_f32_16x16x32_bf16(af1, b10, acc0, 0, 0, 0);
      acc1 = __builtin_amdgcn_mfma_f32_16x16x32_bf16(af1, b11, acc1, 0, 0, 0);
    }
    if (t + 1 < NT) { cur0 = nxt0; cur1 = nxt1; cur2 = nxt2; cur3 = nxt3; }
  }

  // epilogue: D[row=m-local=4lg+r][col], cols: acc0->d=wd*32+lr, acc1->d=wd*32+16+lr
#pragma unroll
  for (int f = 0; f < 2; ++f) {
    f32x4 a = f ? acc1 : acc0;
#pragma unroll
    for (int r = 0; r < 4; ++r) {
      int m = m0 + wm * 16 + lg * 4 + r;
      int d = n0 + wd * 32 + f * 16 + lr;
      outb[(size_t)m * D_EMB + d] = (bf)a[r];
    }
  }
}

// ---------- bf16 GEMM, 3-buffer counted-vmcnt pipeline (unchanged from R4) ----------
template <int BM, int BN, bool RELU_BF16>
__global__ __launch_bounds__(256, 3) void k_gemm(const bf* __restrict__ A, const bf* __restrict__ BT,
                                                 const float* __restrict__ bias, void* __restrict__ out,
                                                 int M, int N, int K) {
  constexpr int WM = BM / 2, WN = BN / 2;
  constexpr int FM = WM / 16, FN = WN / 16;
  constexpr int BUF = (BM + BN) * 128;
  __shared__ __align__(16) char sm[3 * BUF];

  const int tid = threadIdx.x;
  const int wave = tid >> 6, lane = tid & 63;
  const int lr = lane & 15, lg = lane >> 4;
  const int wm = wave & 1, wn = wave >> 1;
  const int m0 = blockIdx.x * BM, n0 = blockIdx.y * BN;

  f32x4 acc[FM][FN];
#pragma unroll
  for (int i = 0; i < FM; ++i)
#pragma unroll
    for (int f = 0; f < FN; ++f) acc[i][f] = f32x4{0.f, 0.f, 0.f, 0.f};

  stage_tile<BM>(A + (size_t)m0 * K, K, sm, wave, lane);
  stage_tile<BN>(BT + (size_t)n0 * K, K, sm + BM * 128, wave, lane);
  stage_tile<BM>(A + (size_t)m0 * K + 64, K, sm + BUF, wave, lane);
  stage_tile<BN>(BT + (size_t)n0 * K + 64, K, sm + BUF + BM * 128, wave, lane);

  const int NT = K / 64;
  for (int t = 0; t < NT; ++t) {
    char* aTc = sm + (t % 3) * BUF;
    char* bTc = aTc + BM * 128;
    if (t + 1 < NT) asm volatile("s_waitcnt vmcnt(4)" ::: "memory");
    else            asm volatile("s_waitcnt vmcnt(0)" ::: "memory");
    __builtin_amdgcn_s_barrier();

    if (t + 2 < NT) {
      char* aTn = sm + ((t + 2) % 3) * BUF;
      stage_tile<BM>(A + (size_t)m0 * K + (t + 2) * 64, K, aTn, wave, lane);
      stage_tile<BN>(BT + (size_t)n0 * K + (t + 2) * 64, K, aTn + BM * 128, wave, lane);
    }
#pragma unroll
    for (int ks = 0; ks < 2; ++ks) {
      bf16x8 a[FM], b[FN];
#pragma unroll
      for (int i = 0; i < FM; ++i) a[i] = ldf128(aTc, wm * WM + i * 16 + lr, (ks * 32 + lg * 8) * 2);
#pragma unroll
      for (int f = 0; f < FN; ++f) b[f] = ldf128(bTc, wn * WN + f * 16 + lr, (ks * 32 + lg * 8) * 2);
#pragma unroll
      for (int i = 0; i < FM; ++i)
#pragma unroll
        for (int f = 0; f < FN; ++f)
          acc[i][f] = __builtin_amdgcn_mfma_f32_16x16x32_bf16(a[i], b[f], acc[i][f], 0, 0, 0);
    }
  }

#pragma unroll
  for (int f = 0; f < FN; ++f) {
    int n = n0 + wn * WN + f * 16 + lr;
    float bv = bias[n];
#pragma unroll
    for (int i = 0; i < FM; ++i)
#pragma unroll
      for (int r = 0; r < 4; ++r) {
        int m = m0 + wm * WM + i * 16 + lg * 4 + r;
        float v = acc[i][f][r] + bv;
        if (RELU_BF16) {
          v = v > 0.f ? v : 0.f;
          ((bf*)out)[(size_t)m * N + n] = (bf)v;
        } else {
          ((float*)out)[(size_t)m * N + n] = v;
        }
      }
  }
}

// ---------- workspace layout ----------
constexpr size_t OFF_PHI   = 0;
constexpr size_t OFF_FLATT = OFF_PHI + (size_t)M_TOT * 32 * 2;
constexpr size_t OFF_OUTB  = OFF_FLATT + (size_t)D_EMB * M_TOT * 2;
constexpr size_t OFF_W1T   = OFF_OUTB + (size_t)M_TOT * D_EMB * 2;
constexpr size_t OFF_W2T   = OFF_W1T + (size_t)F_FFN * D_EMB * 2;
constexpr size_t OFF_HB    = OFF_W2T + (size_t)D_EMB * F_FFN * 2;

extern "C" void kernel_launch(void* const* d_in, const int* in_sizes, int n_in,
                              void* d_out, int out_size, void* d_ws, size_t ws_size,
                              hipStream_t stream) {
  const float* x  = (const float*)d_in[0];
  const float* W1 = (const float*)d_in[1];
  const float* b1 = (const float*)d_in[2];
  const float* W2 = (const float*)d_in[3];
  const float* b2 = (const float*)d_in[4];
  float* y = (float*)d_out;
  char* ws = (char*)d_ws;

  bf* phib  = (bf*)(ws + OFF_PHI);
  bf* flatTp = (bf*)(ws + OFF_FLATT);   // column-permuted flat^T
  bf* outb  = (bf*)(ws + OFF_OUTB);
  bf* w1T   = (bf*)(ws + OFF_W1T);
  bf* w2T   = (bf*)(ws + OFF_W2T);
  bf* hb    = (bf*)(ws + OFF_HB);

  k_phi<<<M_TOT / 256, 256, 0, stream>>>(x, phib);
  k_transpose_cvt<true ><<<dim3(D_EMB / 32, M_TOT / 32), dim3(32, 8), 0, stream>>>(x, flatTp, M_TOT, D_EMB);
  k_transpose_cvt<false><<<dim3(F_FFN / 32, D_EMB / 32), dim3(32, 8), 0, stream>>>(W1, w1T, D_EMB, F_FFN);
  k_transpose_cvt<false><<<dim3(D_EMB / 32, F_FFN / 32), dim3(32, 8), 0, stream>>>(W2, w2T, F_FFN, D_EMB);

  // fused gram @ flat: 32m x 64d blocks, 1024 blocks (4/CU)
  k_gram<<<dim3(1024), 256, 0, stream>>>(phib, flatTp, outb);

  k_gemm<64, 64, true ><<<dim3(M_TOT / 64, F_FFN / 64), 256, 0, stream>>>(outb, w1T, b1, (void*)hb, M_TOT, F_FFN, D_EMB);
  k_gemm<64, 64, false><<<dim3(M_TOT / 64, D_EMB / 64), 256, 0, stream>>>(hb, w2T, b2, (void*)y, M_TOT, D_EMB, F_FFN);
}

// Round 6
// 89.994 us; speedup vs baseline: 1.4564x; 1.4564x over previous
//
#include <hip/hip_runtime.h>
#include <hip/hip_bf16.h>
#include <stdint.h>

using bf = __bf16;
typedef __attribute__((ext_vector_type(8))) __bf16 bf16x8;
typedef __attribute__((ext_vector_type(4))) float f32x4;

#define M_TOT 4096
#define D_EMB 512
#define F_FFN 2048

// ---------- async global->LDS, 16B per lane ----------
__device__ __forceinline__ void gload_lds16(const void* g, void* l) {
  __builtin_amdgcn_global_load_lds(
      (const __attribute__((address_space(1))) uint32_t*)g,
      (__attribute__((address_space(3))) uint32_t*)l, 16, 0, 0);
}

// ---------- 128B-row swizzled tiles (K-step 64) ----------
__device__ __forceinline__ int swz128(int row, int b) {
  return row * 128 + (b ^ ((row & 7) << 4));
}
__device__ __forceinline__ bf16x8 ldf128(const char* base, int row, int b) {
  return *(const bf16x8*)(base + swz128(row, b));
}
// linear LDS dest + inverse-swizzled global source chunk (rule #21)
template <int ROWS>
__device__ __forceinline__ void stage_tile(const bf* gsrc, int ld, char* lbase, int wave, int lane) {
  const int rsub = lane >> 3, csub = lane & 7;
#pragma unroll
  for (int i = 0; i < ROWS / 32; ++i) {
    int chunk = wave + i * 4;
    int row = chunk * 8 + rsub;
    int sc = csub ^ (row & 7);
    gload_lds16((const char*)gsrc + (size_t)row * (size_t)(ld * 2) + sc * 16, lbase + chunk * 1024);
  }
}

// ---------- prep: phi features (rank-16 factorization of the gram) ----------
__global__ __launch_bounds__(256) void k_phi(const float* __restrict__ x, bf* __restrict__ phib) {
  int i = blockIdx.x * 256 + threadIdx.x;
  float c[4], s[4];
#pragma unroll
  for (int k = 0; k < 4; ++k) {
    float f = x[(size_t)i * D_EMB + k] * 0.5f;
    sincosf(f, &s[k], &c[k]);
  }
#pragma unroll
  for (int m = 0; m < 16; ++m) {
    float p = 1.0f;
#pragma unroll
    for (int k = 0; k < 4; ++k) p *= ((m >> k) & 1) ? s[k] : c[k];
    phib[(size_t)i * 32 + m] = (bf)p;
  }
#pragma unroll
  for (int m = 16; m < 32; ++m) phib[(size_t)i * 32 + m] = (bf)0.0f;
}

// ---------- prep: transpose + convert f32 -> bf16 ----------
__global__ __launch_bounds__(256) void k_transpose_cvt(const float* __restrict__ in,
                                                       bf* __restrict__ out, int R, int C) {
  __shared__ float tile[32][33];
  int c0 = blockIdx.x * 32, r0 = blockIdx.y * 32;
  int tx = threadIdx.x, ty = threadIdx.y;
#pragma unroll
  for (int i = 0; i < 32; i += 8)
    tile[ty + i][tx] = in[(size_t)(r0 + ty + i) * C + c0 + tx];
  __syncthreads();
#pragma unroll
  for (int i = 0; i < 32; i += 8)
    out[(size_t)(c0 + ty + i) * R + r0 + tx] = (bf)tile[tx][ty + i];
}

// ---------- S = |Phi Phi^T| materialized, no duplication ----------
// 128m x 128j per block, 4 waves (32m strips), phi straight from L2. 1024 blocks.
__global__ __launch_bounds__(256, 4) void k_sgen(const bf* __restrict__ phib, bf* __restrict__ S) {
  const int lin = blockIdx.x;
  const int m0 = (lin & 31) * 128;
  const int j0 = (lin >> 5) * 128;
  const int wave = threadIdx.x >> 6, lane = threadIdx.x & 63;
  const int lr = lane & 15, lg = lane >> 4;

  const bf* pm = phib + (size_t)(m0 + wave * 32) * 32;
  const bf16x8 a0 = *(const bf16x8*)(pm + (size_t)lr * 32 + lg * 8);
  const bf16x8 a1 = *(const bf16x8*)(pm + (size_t)(16 + lr) * 32 + lg * 8);

#pragma unroll
  for (int jf = 0; jf < 8; ++jf) {
    bf16x8 b = *(const bf16x8*)(phib + (size_t)(j0 + jf * 16 + lr) * 32 + lg * 8);
    f32x4 s0 = __builtin_amdgcn_mfma_f32_16x16x32_bf16(a0, b, f32x4{0.f, 0.f, 0.f, 0.f}, 0, 0, 0);
    f32x4 s1 = __builtin_amdgcn_mfma_f32_16x16x32_bf16(a1, b, f32x4{0.f, 0.f, 0.f, 0.f}, 0, 0, 0);
    int col = j0 + jf * 16 + lr;
#pragma unroll
    for (int r = 0; r < 4; ++r) {
      S[(size_t)(m0 + wave * 32 + lg * 4 + r) * M_TOT + col] = (bf)fabsf(s0[r]);
      S[(size_t)(m0 + wave * 32 + 16 + lg * 4 + r) * M_TOT + col] = (bf)fabsf(s1[r]);
    }
  }
}

// ---------- bf16 GEMM, 3-buffer counted-vmcnt pipeline ----------
// OUTMODE: 0 = f32 + bias, 1 = bf16 relu + bias, 2 = bf16 plain (no bias)
template <int BM, int BN, int OUTMODE>
__global__ __launch_bounds__(256, 3) void k_gemm(const bf* __restrict__ A, const bf* __restrict__ BT,
                                                 const float* __restrict__ bias, void* __restrict__ out,
                                                 int M, int N, int K) {
  constexpr int WM = BM / 2, WN = BN / 2;
  constexpr int FM = WM / 16, FN = WN / 16;
  constexpr int BUF = (BM + BN) * 128;
  constexpr int LPS = (BM + BN) / 32;  // per-thread loads per stage pair
  static_assert(LPS == 4 || LPS == 6, "vmcnt literal");
  __shared__ __align__(16) char sm[3 * BUF];

  const int tid = threadIdx.x;
  const int wave = tid >> 6, lane = tid & 63;
  const int lr = lane & 15, lg = lane >> 4;
  const int wm = wave & 1, wn = wave >> 1;
  const int m0 = blockIdx.x * BM, n0 = blockIdx.y * BN;

  f32x4 acc[FM][FN];
#pragma unroll
  for (int i = 0; i < FM; ++i)
#pragma unroll
    for (int f = 0; f < FN; ++f) acc[i][f] = f32x4{0.f, 0.f, 0.f, 0.f};

  stage_tile<BM>(A + (size_t)m0 * K, K, sm, wave, lane);
  stage_tile<BN>(BT + (size_t)n0 * K, K, sm + BM * 128, wave, lane);
  stage_tile<BM>(A + (size_t)m0 * K + 64, K, sm + BUF, wave, lane);
  stage_tile<BN>(BT + (size_t)n0 * K + 64, K, sm + BUF + BM * 128, wave, lane);

  const int NT = K / 64;
  for (int t = 0; t < NT; ++t) {
    char* aTc = sm + (t % 3) * BUF;
    char* bTc = aTc + BM * 128;
    if (t + 1 < NT) {
      if constexpr (LPS == 4) asm volatile("s_waitcnt vmcnt(4)" ::: "memory");
      else                    asm volatile("s_waitcnt vmcnt(6)" ::: "memory");
    } else {
      asm volatile("s_waitcnt vmcnt(0)" ::: "memory");
    }
    __builtin_amdgcn_s_barrier();

    if (t + 2 < NT) {
      char* aTn = sm + ((t + 2) % 3) * BUF;
      stage_tile<BM>(A + (size_t)m0 * K + (t + 2) * 64, K, aTn, wave, lane);
      stage_tile<BN>(BT + (size_t)n0 * K + (t + 2) * 64, K, aTn + BM * 128, wave, lane);
    }
#pragma unroll
    for (int ks = 0; ks < 2; ++ks) {
      bf16x8 a[FM], b[FN];
#pragma unroll
      for (int i = 0; i < FM; ++i) a[i] = ldf128(aTc, wm * WM + i * 16 + lr, (ks * 32 + lg * 8) * 2);
#pragma unroll
      for (int f = 0; f < FN; ++f) b[f] = ldf128(bTc, wn * WN + f * 16 + lr, (ks * 32 + lg * 8) * 2);
#pragma unroll
      for (int i = 0; i < FM; ++i)
#pragma unroll
        for (int f = 0; f < FN; ++f)
          acc[i][f] = __builtin_amdgcn_mfma_f32_16x16x32_bf16(a[i], b[f], acc[i][f], 0, 0, 0);
    }
  }

#pragma unroll
  for (int f = 0; f < FN; ++f) {
    int n = n0 + wn * WN + f * 16 + lr;
    float bv = (OUTMODE == 2) ? 0.f : bias[n];
#pragma unroll
    for (int i = 0; i < FM; ++i)
#pragma unroll
      for (int r = 0; r < 4; ++r) {
        int m = m0 + wm * WM + i * 16 + lg * 4 + r;
        float v = acc[i][f][r] + bv;
        if (OUTMODE == 1) {
          v = v > 0.f ? v : 0.f;
          ((bf*)out)[(size_t)m * N + n] = (bf)v;
        } else if (OUTMODE == 2) {
          ((bf*)out)[(size_t)m * N + n] = (bf)v;
        } else {
          ((float*)out)[(size_t)m * N + n] = v;
        }
      }
  }
}

// ---------- workspace layout ----------
// S (32MB) and hb (16MB) share a region: S is dead before gemm1 writes hb.
constexpr size_t OFF_PHI   = 0;
constexpr size_t OFF_FLATT = OFF_PHI + (size_t)M_TOT * 32 * 2;
constexpr size_t OFF_OUTB  = OFF_FLATT + (size_t)D_EMB * M_TOT * 2;
constexpr size_t OFF_W1T   = OFF_OUTB + (size_t)M_TOT * D_EMB * 2;
constexpr size_t OFF_W2T   = OFF_W1T + (size_t)F_FFN * D_EMB * 2;
constexpr size_t OFF_S     = OFF_W2T + (size_t)D_EMB * F_FFN * 2;
constexpr size_t OFF_HB    = OFF_S;  // shared

extern "C" void kernel_launch(void* const* d_in, const int* in_sizes, int n_in,
                              void* d_out, int out_size, void* d_ws, size_t ws_size,
                              hipStream_t stream) {
  const float* x  = (const float*)d_in[0];
  const float* W1 = (const float*)d_in[1];
  const float* b1 = (const float*)d_in[2];
  const float* W2 = (const float*)d_in[3];
  const float* b2 = (const float*)d_in[4];
  float* y = (float*)d_out;
  char* ws = (char*)d_ws;

  bf* phib  = (bf*)(ws + OFF_PHI);
  bf* flatT = (bf*)(ws + OFF_FLATT);
  bf* outb  = (bf*)(ws + OFF_OUTB);
  bf* w1T   = (bf*)(ws + OFF_W1T);
  bf* w2T   = (bf*)(ws + OFF_W2T);
  bf* S     = (bf*)(ws + OFF_S);
  bf* hb    = (bf*)(ws + OFF_HB);

  k_phi<<<M_TOT / 256, 256, 0, stream>>>(x, phib);
  k_transpose_cvt<<<dim3(D_EMB / 32, M_TOT / 32), dim3(32, 8), 0, stream>>>(x, flatT, M_TOT, D_EMB);
  k_transpose_cvt<<<dim3(F_FFN / 32, D_EMB / 32), dim3(32, 8), 0, stream>>>(W1, w1T, D_EMB, F_FFN);
  k_transpose_cvt<<<dim3(D_EMB / 32, F_FFN / 32), dim3(32, 8), 0, stream>>>(W2, w2T, F_FFN, D_EMB);

  // gram stage: materialize S, then plain GEMM
  k_sgen<<<dim3(1024), 256, 0, stream>>>(phib, S);
  k_gemm<64, 64, 2><<<dim3(M_TOT / 64, D_EMB / 64), 256, 0, stream>>>(S, flatT, nullptr, (void*)outb, M_TOT, D_EMB, M_TOT);

  // FFN
  k_gemm<128, 64, 1><<<dim3(M_TOT / 128, F_FFN / 64), 256, 0, stream>>>(outb, w1T, b1, (void*)hb, M_TOT, F_FFN, D_EMB);
  k_gemm<64, 64, 0><<<dim3(M_TOT / 64, D_EMB / 64), 256, 0, stream>>>(hb, w2T, b2, (void*)y, M_TOT, D_EMB, F_FFN);
}

// Round 7
// 89.021 us; speedup vs baseline: 1.4724x; 1.0109x over previous
//
#include <hip/hip_runtime.h>
#include <hip/hip_bf16.h>
#include <stdint.h>

using bf = __bf16;
typedef __attribute__((ext_vector_type(8))) __bf16 bf16x8;
typedef __attribute__((ext_vector_type(4))) float f32x4;

#define M_TOT 4096
#define D_EMB 512
#define F_FFN 2048

// ---------- async global->LDS, 16B per lane ----------
__device__ __forceinline__ void gload_lds16(const void* g, void* l) {
  __builtin_amdgcn_global_load_lds(
      (const __attribute__((address_space(1))) uint32_t*)g,
      (__attribute__((address_space(3))) uint32_t*)l, 16, 0, 0);
}

// ---------- 128B-row swizzled tiles (K-step 64) ----------
__device__ __forceinline__ int swz128(int row, int b) {
  return row * 128 + (b ^ ((row & 7) << 4));
}
__device__ __forceinline__ bf16x8 ldf128(const char* base, int row, int b) {
  return *(const bf16x8*)(base + swz128(row, b));
}
// linear LDS dest + inverse-swizzled global source chunk (rule #21)
template <int ROWS>
__device__ __forceinline__ void stage_tile(const bf* gsrc, int ld, char* lbase, int wave, int lane) {
  const int rsub = lane >> 3, csub = lane & 7;
#pragma unroll
  for (int i = 0; i < ROWS / 32; ++i) {
    int chunk = wave + i * 4;
    int row = chunk * 8 + rsub;
    int sc = csub ^ (row & 7);
    gload_lds16((const char*)gsrc + (size_t)row * (size_t)(ld * 2) + sc * 16, lbase + chunk * 1024);
  }
}

// ---------- prep: phi features (rank-16 factorization of the gram) ----------
__global__ __launch_bounds__(256) void k_phi(const float* __restrict__ x, bf* __restrict__ phib) {
  int i = blockIdx.x * 256 + threadIdx.x;
  float c[4], s[4];
#pragma unroll
  for (int k = 0; k < 4; ++k) {
    float f = x[(size_t)i * D_EMB + k] * 0.5f;
    sincosf(f, &s[k], &c[k]);
  }
#pragma unroll
  for (int m = 0; m < 16; ++m) {
    float p = 1.0f;
#pragma unroll
    for (int k = 0; k < 4; ++k) p *= ((m >> k) & 1) ? s[k] : c[k];
    phib[(size_t)i * 32 + m] = (bf)p;
  }
#pragma unroll
  for (int m = 16; m < 32; ++m) phib[(size_t)i * 32 + m] = (bf)0.0f;
}

// ---------- prep: transpose + convert f32 -> bf16 ----------
__global__ __launch_bounds__(256) void k_transpose_cvt(const float* __restrict__ in,
                                                       bf* __restrict__ out, int R, int C) {
  __shared__ float tile[32][33];
  int c0 = blockIdx.x * 32, r0 = blockIdx.y * 32;
  int tx = threadIdx.x, ty = threadIdx.y;
#pragma unroll
  for (int i = 0; i < 32; i += 8)
    tile[ty + i][tx] = in[(size_t)(r0 + ty + i) * C + c0 + tx];
  __syncthreads();
#pragma unroll
  for (int i = 0; i < 32; i += 8)
    out[(size_t)(c0 + ty + i) * R + r0 + tx] = (bf)tile[tx][ty + i];
}

// ---------- S = |Phi Phi^T| materialized, no duplication ----------
__global__ __launch_bounds__(256, 4) void k_sgen(const bf* __restrict__ phib, bf* __restrict__ S) {
  const int lin = blockIdx.x;
  const int m0 = (lin & 31) * 128;
  const int j0 = (lin >> 5) * 128;
  const int wave = threadIdx.x >> 6, lane = threadIdx.x & 63;
  const int lr = lane & 15, lg = lane >> 4;

  const bf* pm = phib + (size_t)(m0 + wave * 32) * 32;
  const bf16x8 a0 = *(const bf16x8*)(pm + (size_t)lr * 32 + lg * 8);
  const bf16x8 a1 = *(const bf16x8*)(pm + (size_t)(16 + lr) * 32 + lg * 8);

#pragma unroll
  for (int jf = 0; jf < 8; ++jf) {
    bf16x8 b = *(const bf16x8*)(phib + (size_t)(j0 + jf * 16 + lr) * 32 + lg * 8);
    f32x4 s0 = __builtin_amdgcn_mfma_f32_16x16x32_bf16(a0, b, f32x4{0.f, 0.f, 0.f, 0.f}, 0, 0, 0);
    f32x4 s1 = __builtin_amdgcn_mfma_f32_16x16x32_bf16(a1, b, f32x4{0.f, 0.f, 0.f, 0.f}, 0, 0, 0);
    int col = j0 + jf * 16 + lr;
#pragma unroll
    for (int r = 0; r < 4; ++r) {
      S[(size_t)(m0 + wave * 32 + lg * 4 + r) * M_TOT + col] = (bf)fabsf(s0[r]);
      S[(size_t)(m0 + wave * 32 + 16 + lg * 4 + r) * M_TOT + col] = (bf)fabsf(s1[r]);
    }
  }
}

// ---------- bf16 GEMM: 2-buffer 2-barrier counted-vmcnt, m97 wave geometry ----------
// 1D grid, bijective XCD remap: lin -> e=lin&7 (XCD), j=lin>>3;
// bm = e*4 + (j&3), bn = j>>2. Requires M/BM == 32.
// OUTMODE: 0 = f32 + bias, 1 = bf16 relu + bias, 2 = bf16 plain (no bias)
template <int BM, int BN, int OUTMODE>
__global__ __launch_bounds__(256, 2) void k_gemm(const bf* __restrict__ A, const bf* __restrict__ BT,
                                                 const float* __restrict__ bias, void* __restrict__ out,
                                                 int M, int N, int K) {
  constexpr int WM = BM / 2, WN = BN / 2;
  constexpr int FM = WM / 16, FN = WN / 16;
  constexpr int ABUF = BM * 128, BBUF = BN * 128, BUF = ABUF + BBUF;
  constexpr int LP = (BM + BN) / 32;  // per-thread gload_lds per stage pair
  static_assert(LP == 6 || LP == 8, "vmcnt literal");
  __shared__ __align__(16) char sm[2 * BUF];

  const int tid = threadIdx.x;
  const int wave = tid >> 6, lane = tid & 63;
  const int lr = lane & 15, lg = lane >> 4;
  const int wm = wave & 1, wn = wave >> 1;

  const int lin = blockIdx.x;
  const int bm = (lin & 7) * 4 + ((lin >> 3) & 3);
  const int bn = lin >> 5;
  const int m0 = bm * BM, n0 = bn * BN;

  f32x4 acc[FM][FN];
#pragma unroll
  for (int i = 0; i < FM; ++i)
#pragma unroll
    for (int f = 0; f < FN; ++f) acc[i][f] = f32x4{0.f, 0.f, 0.f, 0.f};

  // prologue: stage t=0 -> buf0, t=1 -> buf1
  stage_tile<BM>(A + (size_t)m0 * K, K, sm, wave, lane);
  stage_tile<BN>(BT + (size_t)n0 * K, K, sm + ABUF, wave, lane);
  stage_tile<BM>(A + (size_t)m0 * K + 64, K, sm + BUF, wave, lane);
  stage_tile<BN>(BT + (size_t)n0 * K + 64, K, sm + BUF + ABUF, wave, lane);

  const int NT = K / 64;
  for (int t = 0; t < NT; ++t) {
    char* aTc = sm + (t & 1) * BUF;
    char* bTc = aTc + ABUF;
    // own-wave stage(t) complete: outstanding newer = stage(t+1) [+ stage(t+2)]
    if (t + 1 < NT) {
      if constexpr (LP == 6) asm volatile("s_waitcnt vmcnt(6)" ::: "memory");
      else                   asm volatile("s_waitcnt vmcnt(8)" ::: "memory");
    } else {
      asm volatile("s_waitcnt vmcnt(0)" ::: "memory");
    }
    __builtin_amdgcn_s_barrier();

#pragma unroll
    for (int ks = 0; ks < 2; ++ks) {
      bf16x8 a[FM], b[FN];
#pragma unroll
      for (int i = 0; i < FM; ++i) a[i] = ldf128(aTc, wm * WM + i * 16 + lr, (ks * 32 + lg * 8) * 2);
#pragma unroll
      for (int f = 0; f < FN; ++f) b[f] = ldf128(bTc, wn * WN + f * 16 + lr, (ks * 32 + lg * 8) * 2);
#pragma unroll
      for (int i = 0; i < FM; ++i)
#pragma unroll
        for (int f = 0; f < FN; ++f)
          acc[i][f] = __builtin_amdgcn_mfma_f32_16x16x32_bf16(a[i], b[f], acc[i][f], 0, 0, 0);
    }
    __builtin_amdgcn_s_barrier();  // all waves done reading buf (t&1)
    if (t + 2 < NT) {              // refill the buffer just consumed
      char* aTn = sm + (t & 1) * BUF;
      stage_tile<BM>(A + (size_t)m0 * K + (t + 2) * 64, K, aTn, wave, lane);
      stage_tile<BN>(BT + (size_t)n0 * K + (t + 2) * 64, K, aTn + ABUF, wave, lane);
    }
  }

#pragma unroll
  for (int f = 0; f < FN; ++f) {
    int n = n0 + wn * WN + f * 16 + lr;
    float bv = (OUTMODE == 2) ? 0.f : bias[n];
#pragma unroll
    for (int i = 0; i < FM; ++i)
#pragma unroll
      for (int r = 0; r < 4; ++r) {
        int m = m0 + wm * WM + i * 16 + lg * 4 + r;
        float v = acc[i][f][r] + bv;
        if (OUTMODE == 1) {
          v = v > 0.f ? v : 0.f;
          ((bf*)out)[(size_t)m * N + n] = (bf)v;
        } else if (OUTMODE == 2) {
          ((bf*)out)[(size_t)m * N + n] = (bf)v;
        } else {
          ((float*)out)[(size_t)m * N + n] = v;
        }
      }
  }
}

// ---------- workspace layout ----------
// S (32MB) and hb (16MB) share a region: S is dead before gemm1 writes hb.
constexpr size_t OFF_PHI   = 0;
constexpr size_t OFF_FLATT = OFF_PHI + (size_t)M_TOT * 32 * 2;
constexpr size_t OFF_OUTB  = OFF_FLATT + (size_t)D_EMB * M_TOT * 2;
constexpr size_t OFF_W1T   = OFF_OUTB + (size_t)M_TOT * D_EMB * 2;
constexpr size_t OFF_W2T   = OFF_W1T + (size_t)F_FFN * D_EMB * 2;
constexpr size_t OFF_S     = OFF_W2T + (size_t)D_EMB * F_FFN * 2;
constexpr size_t OFF_HB    = OFF_S;  // shared

extern "C" void kernel_launch(void* const* d_in, const int* in_sizes, int n_in,
                              void* d_out, int out_size, void* d_ws, size_t ws_size,
                              hipStream_t stream) {
  const float* x  = (const float*)d_in[0];
  const float* W1 = (const float*)d_in[1];
  const float* b1 = (const float*)d_in[2];
  const float* W2 = (const float*)d_in[3];
  const float* b2 = (const float*)d_in[4];
  float* y = (float*)d_out;
  char* ws = (char*)d_ws;

  bf* phib  = (bf*)(ws + OFF_PHI);
  bf* flatT = (bf*)(ws + OFF_FLATT);
  bf* outb  = (bf*)(ws + OFF_OUTB);
  bf* w1T   = (bf*)(ws + OFF_W1T);
  bf* w2T   = (bf*)(ws + OFF_W2T);
  bf* S     = (bf*)(ws + OFF_S);
  bf* hb    = (bf*)(ws + OFF_HB);

  k_phi<<<M_TOT / 256, 256, 0, stream>>>(x, phib);
  k_transpose_cvt<<<dim3(D_EMB / 32, M_TOT / 32), dim3(32, 8), 0, stream>>>(x, flatT, M_TOT, D_EMB);
  k_transpose_cvt<<<dim3(F_FFN / 32, D_EMB / 32), dim3(32, 8), 0, stream>>>(W1, w1T, D_EMB, F_FFN);
  k_transpose_cvt<<<dim3(D_EMB / 32, F_FFN / 32), dim3(32, 8), 0, stream>>>(W2, w2T, F_FFN, D_EMB);

  // gram stage: materialize S, then plain GEMM (M/BM must be 32 for XCD remap)
  k_sgen<<<dim3(1024), 256, 0, stream>>>(phib, S);
  k_gemm<128, 64, 2><<<dim3(32 * (D_EMB / 64)), 256, 0, stream>>>(S, flatT, nullptr, (void*)outb, M_TOT, D_EMB, M_TOT);

  // FFN
  k_gemm<128, 128, 1><<<dim3(32 * (F_FFN / 128)), 256, 0, stream>>>(outb, w1T, b1, (void*)hb, M_TOT, F_FFN, D_EMB);
  k_gemm<128, 64, 0><<<dim3(32 * (D_EMB / 64)), 256, 0, stream>>>(hb, w2T, b2, (void*)y, M_TOT, D_EMB, F_FFN);
}

// Round 8
// 83.379 us; speedup vs baseline: 1.5720x; 1.0677x over previous
//
#include <hip/hip_runtime.h>
#include <hip/hip_bf16.h>
#include <stdint.h>

using bf = __bf16;
typedef __attribute__((ext_vector_type(8))) __bf16 bf16x8;
typedef __attribute__((ext_vector_type(4))) float f32x4;

#define M_TOT 4096
#define D_EMB 512
#define F_FFN 2048

// ---------- async global->LDS, 16B per lane ----------
__device__ __forceinline__ void gload_lds16(const void* g, void* l) {
  __builtin_amdgcn_global_load_lds(
      (const __attribute__((address_space(1))) uint32_t*)g,
      (__attribute__((address_space(3))) uint32_t*)l, 16, 0, 0);
}

// ---------- 128B-row swizzled tiles (K-step 64) ----------
__device__ __forceinline__ int swz128(int row, int b) {
  return row * 128 + (b ^ ((row & 7) << 4));
}
__device__ __forceinline__ bf16x8 ldf128(const char* base, int row, int b) {
  return *(const bf16x8*)(base + swz128(row, b));
}
// 8-wave (512-thread) stager: linear LDS dest + inverse-swizzled global source
template <int ROWS>
__device__ __forceinline__ void stage_tile8(const bf* gsrc, int ld, char* lbase, int wave, int lane) {
  const int rsub = lane >> 3, csub = lane & 7;
#pragma unroll
  for (int i = 0; i < ROWS / 64; ++i) {
    int chunk = wave + i * 8;
    int row = chunk * 8 + rsub;
    int sc = csub ^ rsub;
    gload_lds16((const char*)gsrc + (size_t)row * (size_t)(ld * 2) + sc * 16, lbase + chunk * 1024);
  }
}

// ---------- consolidated prep: 3 transposes + phi, one kernel ----------
__device__ __forceinline__ void do_transpose(const float* __restrict__ in, bf* __restrict__ out,
                                             int R, int C, int tileIdx, int tid, float tile[32][33]) {
  int tilesX = C / 32;
  int c0 = (tileIdx % tilesX) * 32, r0 = (tileIdx / tilesX) * 32;
  int tx = tid & 31, ty = tid >> 5;  // 32 x 8
#pragma unroll
  for (int i = 0; i < 32; i += 8)
    tile[ty + i][tx] = in[(size_t)(r0 + ty + i) * C + c0 + tx];
  __syncthreads();
#pragma unroll
  for (int i = 0; i < 32; i += 8)
    out[(size_t)(c0 + ty + i) * R + r0 + tx] = (bf)tile[tx][ty + i];
}

#define NT_FT  2048  // flatT tiles: (512/32)*(4096/32)
#define NT_W1  1024  // w1T: (2048/32)*(512/32)
#define NT_W2  1024  // w2T: (512/32)*(2048/32)
#define NT_PHI 16

__global__ __launch_bounds__(256) void k_prep(const float* __restrict__ x,
                                              const float* __restrict__ W1,
                                              const float* __restrict__ W2,
                                              bf* __restrict__ flatT, bf* __restrict__ w1T,
                                              bf* __restrict__ w2T, bf* __restrict__ phib) {
  __shared__ float tile[32][33];
  const int bid = blockIdx.x, tid = threadIdx.x;
  if (bid < NT_FT) {
    do_transpose(x, flatT, M_TOT, D_EMB, bid, tid, tile);
  } else if (bid < NT_FT + NT_W1) {
    do_transpose(W1, w1T, D_EMB, F_FFN, bid - NT_FT, tid, tile);
  } else if (bid < NT_FT + NT_W1 + NT_W2) {
    do_transpose(W2, w2T, F_FFN, D_EMB, bid - NT_FT - NT_W1, tid, tile);
  } else {
    int i = (bid - NT_FT - NT_W1 - NT_W2) * 256 + tid;
    float c[4], s[4];
#pragma unroll
    for (int k = 0; k < 4; ++k) {
      float f = x[(size_t)i * D_EMB + k] * 0.5f;
      sincosf(f, &s[k], &c[k]);
    }
#pragma unroll
    for (int m = 0; m < 16; ++m) {
      float p = 1.0f;
#pragma unroll
      for (int k = 0; k < 4; ++k) p *= ((m >> k) & 1) ? s[k] : c[k];
      phib[(size_t)i * 32 + m] = (bf)p;
    }
#pragma unroll
    for (int m = 16; m < 32; ++m) phib[(size_t)i * 32 + m] = (bf)0.0f;
  }
}

// ---------- S = |Phi Phi^T| materialized, no duplication ----------
__global__ __launch_bounds__(256, 4) void k_sgen(const bf* __restrict__ phib, bf* __restrict__ S) {
  const int lin = blockIdx.x;
  const int m0 = (lin & 31) * 128;
  const int j0 = (lin >> 5) * 128;
  const int wave = threadIdx.x >> 6, lane = threadIdx.x & 63;
  const int lr = lane & 15, lg = lane >> 4;

  const bf* pm = phib + (size_t)(m0 + wave * 32) * 32;
  const bf16x8 a0 = *(const bf16x8*)(pm + (size_t)lr * 32 + lg * 8);
  const bf16x8 a1 = *(const bf16x8*)(pm + (size_t)(16 + lr) * 32 + lg * 8);

#pragma unroll
  for (int jf = 0; jf < 8; ++jf) {
    bf16x8 b = *(const bf16x8*)(phib + (size_t)(j0 + jf * 16 + lr) * 32 + lg * 8);
    f32x4 s0 = __builtin_amdgcn_mfma_f32_16x16x32_bf16(a0, b, f32x4{0.f, 0.f, 0.f, 0.f}, 0, 0, 0);
    f32x4 s1 = __builtin_amdgcn_mfma_f32_16x16x32_bf16(a1, b, f32x4{0.f, 0.f, 0.f, 0.f}, 0, 0, 0);
    int col = j0 + jf * 16 + lr;
#pragma unroll
    for (int r = 0; r < 4; ++r) {
      S[(size_t)(m0 + wave * 32 + lg * 4 + r) * M_TOT + col] = (bf)fabsf(s0[r]);
      S[(size_t)(m0 + wave * 32 + 16 + lg * 4 + r) * M_TOT + col] = (bf)fabsf(s1[r]);
    }
  }
}

// ---------- bf16 GEMM: 8 waves, 3-buffer 1-barrier counted-vmcnt ----------
// wave grid 4m x 2n, wave tile 32 x (BN/2). 1D grid with bijective XCD remap
// (requires M/BM == 32). OUTMODE: 0=f32+bias, 1=bf16 relu+bias, 2=bf16 plain.
template <int BM, int BN, int OUTMODE>
__global__ __launch_bounds__(512, 1) void k_gemm8(const bf* __restrict__ A, const bf* __restrict__ BT,
                                                  const float* __restrict__ bias, void* __restrict__ out,
                                                  int M, int N, int K) {
  constexpr int WN = BN / 2;
  constexpr int FM = 2, FN = WN / 16;
  constexpr int ABUF = BM * 128, BBUF = BN * 128, BUF = ABUF + BBUF;
  constexpr int LP = BM / 64 + BN / 64;  // per-wave gload_lds per stage pair
  static_assert(LP == 3 || LP == 4, "vmcnt literal");
  __shared__ __align__(16) char sm[3 * BUF];

  const int tid = threadIdx.x;
  const int wave = tid >> 6, lane = tid & 63;
  const int lr = lane & 15, lg = lane >> 4;
  const int wm = wave >> 1, wn = wave & 1;

  const int lin = blockIdx.x;
  const int e = lin & 7, jj = lin >> 3;
  const int nbn = N / BN;
  const int bm = e * 4 + jj / nbn, bn = jj % nbn;
  const int m0 = bm * BM, n0 = bn * BN;

  f32x4 acc[FM][FN];
#pragma unroll
  for (int i = 0; i < FM; ++i)
#pragma unroll
    for (int f = 0; f < FN; ++f) acc[i][f] = f32x4{0.f, 0.f, 0.f, 0.f};

  // prologue: stage t=0 -> buf0, t=1 -> buf1
  stage_tile8<BM>(A + (size_t)m0 * K, K, sm, wave, lane);
  stage_tile8<BN>(BT + (size_t)n0 * K, K, sm + ABUF, wave, lane);
  stage_tile8<BM>(A + (size_t)m0 * K + 64, K, sm + BUF, wave, lane);
  stage_tile8<BN>(BT + (size_t)n0 * K + 64, K, sm + BUF + ABUF, wave, lane);

  const int NT = K / 64;
  for (int t = 0; t < NT; ++t) {
    char* aTc = sm + (t % 3) * BUF;
    char* bTc = aTc + ABUF;
    // stage(t) done when everything but stage(t+1) (LP loads) has retired
    if (t + 1 < NT) {
      if constexpr (LP == 3) asm volatile("s_waitcnt vmcnt(3)" ::: "memory");
      else                   asm volatile("s_waitcnt vmcnt(4)" ::: "memory");
    } else {
      asm volatile("s_waitcnt vmcnt(0)" ::: "memory");
    }
    __builtin_amdgcn_s_barrier();

    if (t + 2 < NT) {  // refill buf (t+2)%3 == the one compute(t-1) just freed
      char* aTn = sm + ((t + 2) % 3) * BUF;
      stage_tile8<BM>(A + (size_t)m0 * K + (t + 2) * 64, K, aTn, wave, lane);
      stage_tile8<BN>(BT + (size_t)n0 * K + (t + 2) * 64, K, aTn + ABUF, wave, lane);
    }
#pragma unroll
    for (int ks = 0; ks < 2; ++ks) {
      bf16x8 a[FM], b[FN];
#pragma unroll
      for (int i = 0; i < FM; ++i) a[i] = ldf128(aTc, wm * 32 + i * 16 + lr, (ks * 32 + lg * 8) * 2);
#pragma unroll
      for (int f = 0; f < FN; ++f) b[f] = ldf128(bTc, wn * WN + f * 16 + lr, (ks * 32 + lg * 8) * 2);
#pragma unroll
      for (int i = 0; i < FM; ++i)
#pragma unroll
        for (int f = 0; f < FN; ++f)
          acc[i][f] = __builtin_amdgcn_mfma_f32_16x16x32_bf16(a[i], b[f], acc[i][f], 0, 0, 0);
    }
  }

#pragma unroll
  for (int f = 0; f < FN; ++f) {
    int n = n0 + wn * WN + f * 16 + lr;
    float bv = (OUTMODE == 2) ? 0.f : bias[n];
#pragma unroll
    for (int i = 0; i < FM; ++i)
#pragma unroll
      for (int r = 0; r < 4; ++r) {
        int m = m0 + wm * 32 + i * 16 + lg * 4 + r;
        float v = acc[i][f][r] + bv;
        if (OUTMODE == 1) {
          v = v > 0.f ? v : 0.f;
          ((bf*)out)[(size_t)m * N + n] = (bf)v;
        } else if (OUTMODE == 2) {
          ((bf*)out)[(size_t)m * N + n] = (bf)v;
        } else {
          ((float*)out)[(size_t)m * N + n] = v;
        }
      }
  }
}

// ---------- workspace layout ----------
// S (32MB) and hb (16MB) share a region: S is dead before gemm1 writes hb.
constexpr size_t OFF_PHI   = 0;
constexpr size_t OFF_FLATT = OFF_PHI + (size_t)M_TOT * 32 * 2;
constexpr size_t OFF_OUTB  = OFF_FLATT + (size_t)D_EMB * M_TOT * 2;
constexpr size_t OFF_W1T   = OFF_OUTB + (size_t)M_TOT * D_EMB * 2;
constexpr size_t OFF_W2T   = OFF_W1T + (size_t)F_FFN * D_EMB * 2;
constexpr size_t OFF_S     = OFF_W2T + (size_t)D_EMB * F_FFN * 2;
constexpr size_t OFF_HB    = OFF_S;  // shared

extern "C" void kernel_launch(void* const* d_in, const int* in_sizes, int n_in,
                              void* d_out, int out_size, void* d_ws, size_t ws_size,
                              hipStream_t stream) {
  const float* x  = (const float*)d_in[0];
  const float* W1 = (const float*)d_in[1];
  const float* b1 = (const float*)d_in[2];
  const float* W2 = (const float*)d_in[3];
  const float* b2 = (const float*)d_in[4];
  float* y = (float*)d_out;
  char* ws = (char*)d_ws;

  bf* phib  = (bf*)(ws + OFF_PHI);
  bf* flatT = (bf*)(ws + OFF_FLATT);
  bf* outb  = (bf*)(ws + OFF_OUTB);
  bf* w1T   = (bf*)(ws + OFF_W1T);
  bf* w2T   = (bf*)(ws + OFF_W2T);
  bf* S     = (bf*)(ws + OFF_S);
  bf* hb    = (bf*)(ws + OFF_HB);

  // one consolidated prep kernel (3 transposes + phi)
  k_prep<<<dim3(NT_FT + NT_W1 + NT_W2 + NT_PHI), 256, 0, stream>>>(x, W1, W2, flatT, w1T, w2T, phib);

  // gram stage: materialize S, then plain GEMMs
  k_sgen<<<dim3(1024), 256, 0, stream>>>(phib, S);
  k_gemm8<128, 64, 2><<<dim3(32 * (D_EMB / 64)), 512, 0, stream>>>(S, flatT, nullptr, (void*)outb, M_TOT, D_EMB, M_TOT);

  // FFN
  k_gemm8<128, 128, 1><<<dim3(32 * (F_FFN / 128)), 512, 0, stream>>>(outb, w1T, b1, (void*)hb, M_TOT, F_FFN, D_EMB);
  k_gemm8<128, 64, 0><<<dim3(32 * (D_EMB / 64)), 512, 0, stream>>>(hb, w2T, b2, (void*)y, M_TOT, D_EMB, F_FFN);
}

// Round 9
// 68.153 us; speedup vs baseline: 1.9232x; 1.2234x over previous
//
#include <hip/hip_runtime.h>
#include <hip/hip_bf16.h>
#include <stdint.h>

using bf = __bf16;
typedef __attribute__((ext_vector_type(8))) __bf16 bf16x8;
typedef __attribute__((ext_vector_type(4))) float f32x4;
typedef __attribute__((ext_vector_type(4))) int i32x4;

#define M_TOT 4096
#define D_EMB 512
#define F_FFN 2048

// ---------- async global->LDS, 16B per lane ----------
__device__ __forceinline__ void gload_lds16(const void* g, void* l) {
  __builtin_amdgcn_global_load_lds(
      (const __attribute__((address_space(1))) uint32_t*)g,
      (__attribute__((address_space(3))) uint32_t*)l, 16, 0, 0);
}

// ---------- 128B-row swizzled tiles ----------
__device__ __forceinline__ int swz128(int row, int b) {
  return row * 128 + (b ^ ((row & 7) << 4));
}
__device__ __forceinline__ bf16x8 ldf128(const char* base, int row, int b) {
  return *(const bf16x8*)(base + swz128(row, b));
}
__device__ __forceinline__ i32x4 ldf128i(const char* base, int row, int b) {
  return *(const i32x4*)(base + swz128(row, b));
}
// 8-wave stager: CHUNKS x 1KB (8 rows of 128B); linear LDS dest + inverse-swizzled src
template <int CHUNKS>
__device__ __forceinline__ void stage_rows8(const void* gsrc, size_t ld_bytes, char* lbase,
                                            int wave, int lane) {
  const int rsub = lane >> 3, csub = lane & 7;
  const int sc = csub ^ rsub;
#pragma unroll
  for (int i = 0; i < CHUNKS / 8; ++i) {
    int chunk = wave + i * 8;
    int row = chunk * 8 + rsub;
    gload_lds16((const char*)gsrc + (size_t)row * ld_bytes + sc * 16, lbase + chunk * 1024);
  }
}

__device__ __forceinline__ int quant_i8(float x, float s) {
  float v = x * s;
  v = fminf(127.f, fmaxf(-127.f, v));
  return (int)rintf(v);
}

// ---------- consolidated prep: x->flat_i8^T, W1^T, W2^T (bf16), phi ----------
__device__ __forceinline__ void do_transpose_bf(const float* __restrict__ in, bf* __restrict__ out,
                                                int R, int C, int tileIdx, int tid, float tile[32][33]) {
  int tilesX = C / 32;
  int c0 = (tileIdx % tilesX) * 32, r0 = (tileIdx / tilesX) * 32;
  int tx = tid & 31, ty = tid >> 5;
#pragma unroll
  for (int i = 0; i < 32; i += 8)
    tile[ty + i][tx] = in[(size_t)(r0 + ty + i) * C + c0 + tx];
  __syncthreads();
#pragma unroll
  for (int i = 0; i < 32; i += 8)
    out[(size_t)(c0 + ty + i) * R + r0 + tx] = (bf)tile[tx][ty + i];
}

#define NT_FT  2048
#define NT_W1  1024
#define NT_W2  1024
#define NT_PHI 16

__global__ __launch_bounds__(256) void k_prep(const float* __restrict__ x,
                                              const float* __restrict__ W1,
                                              const float* __restrict__ W2,
                                              int8_t* __restrict__ fi8, bf* __restrict__ w1T,
                                              bf* __restrict__ w2T, bf* __restrict__ phib) {
  __shared__ float tile[32][33];
  const int bid = blockIdx.x, tid = threadIdx.x;
  if (bid < NT_FT) {
    // x (4096 x 512) -> fi8 [d][m] i8, scale 127/8
    int c0 = (bid % (D_EMB / 32)) * 32, r0 = (bid / (D_EMB / 32)) * 32;
    int tx = tid & 31, ty = tid >> 5;
#pragma unroll
    for (int i = 0; i < 32; i += 8)
      tile[ty + i][tx] = x[(size_t)(r0 + ty + i) * D_EMB + c0 + tx];
    __syncthreads();
#pragma unroll
    for (int i = 0; i < 32; i += 8)
      fi8[(size_t)(c0 + ty + i) * M_TOT + r0 + tx] = (int8_t)quant_i8(tile[tx][ty + i], 15.875f);
  } else if (bid < NT_FT + NT_W1) {
    do_transpose_bf(W1, w1T, D_EMB, F_FFN, bid - NT_FT, tid, tile);
  } else if (bid < NT_FT + NT_W1 + NT_W2) {
    do_transpose_bf(W2, w2T, F_FFN, D_EMB, bid - NT_FT - NT_W1, tid, tile);
  } else {
    int i = (bid - NT_FT - NT_W1 - NT_W2) * 256 + tid;
    float c[4], s[4];
#pragma unroll
    for (int k = 0; k < 4; ++k) {
      float f = x[(size_t)i * D_EMB + k] * 0.5f;
      sincosf(f, &s[k], &c[k]);
    }
#pragma unroll
    for (int m = 0; m < 16; ++m) {
      float p = 1.0f;
#pragma unroll
      for (int k = 0; k < 4; ++k) p *= ((m >> k) & 1) ? s[k] : c[k];
      phib[(size_t)i * 32 + m] = (bf)p;
    }
#pragma unroll
    for (int m = 16; m < 32; ++m) phib[(size_t)i * 32 + m] = (bf)0.0f;
  }
}

// ---------- S = round(127*|Phi Phi^T|) as i8, written transposed (S symmetric) ----------
__global__ __launch_bounds__(256, 4) void k_sgen(const bf* __restrict__ phib, int8_t* __restrict__ S) {
  __shared__ __align__(16) char st[16384];  // S^T tile [128 j][128 m] i8, swizzled
  const int lin = blockIdx.x;
  const int m0 = (lin & 31) * 128;
  const int j0 = (lin >> 5) * 128;
  const int tid = threadIdx.x;
  const int wave = tid >> 6, lane = tid & 63;
  const int lr = lane & 15, lg = lane >> 4;

  const bf* pm = phib + (size_t)(m0 + wave * 32) * 32;
  const bf16x8 a0 = *(const bf16x8*)(pm + (size_t)lr * 32 + lg * 8);
  const bf16x8 a1 = *(const bf16x8*)(pm + (size_t)(16 + lr) * 32 + lg * 8);

  const int mb0 = wave * 32 + lg * 4;
  const int key = (lr & 7) << 4;
#pragma unroll
  for (int jf = 0; jf < 8; ++jf) {
    bf16x8 b = *(const bf16x8*)(phib + (size_t)(j0 + jf * 16 + lr) * 32 + lg * 8);
    f32x4 s0 = __builtin_amdgcn_mfma_f32_16x16x32_bf16(a0, b, f32x4{0.f, 0.f, 0.f, 0.f}, 0, 0, 0);
    f32x4 s1 = __builtin_amdgcn_mfma_f32_16x16x32_bf16(a1, b, f32x4{0.f, 0.f, 0.f, 0.f}, 0, 0, 0);
    uint32_t w0 = 0, w1 = 0;
#pragma unroll
    for (int r = 0; r < 4; ++r) {
      uint32_t q0 = (uint32_t)min(127, (int)rintf(fabsf(s0[r]) * 127.f));
      uint32_t q1 = (uint32_t)min(127, (int)rintf(fabsf(s1[r]) * 127.f));
      w0 |= q0 << (8 * r);
      w1 |= q1 << (8 * r);
    }
    int jrow = jf * 16 + lr;
    *(uint32_t*)(st + jrow * 128 + (mb0 ^ key)) = w0;
    *(uint32_t*)(st + jrow * 128 + ((mb0 + 16) ^ key)) = w1;
  }
  __syncthreads();
  // coalesced copy-out to the TRANSPOSED region (valid: S symmetric)
#pragma unroll
  for (int i = 0; i < 4; ++i) {
    int idx = tid + i * 256;
    int jrow = idx >> 3, seg = idx & 7;
    i32x4 v = *(const i32x4*)(st + jrow * 128 + ((seg * 16) ^ ((jrow & 7) << 4)));
    *(i32x4*)(S + (size_t)(j0 + jrow) * M_TOT + m0 + seg * 16) = v;
  }
}

// ---------- i8 GEMM: out = (S/127) @ (flat*127/8)^T * scale, BM64 x BN128 ----------
// 8 waves = 2m x 2n x 2ks (in-block K-slot split, LDS epilogue reduce).
// K-step = 128 bytes, 3-buffer counted-vmcnt (LP=3). Grid 256, XCD-remapped.
__global__ __launch_bounds__(512, 1) void k_gemmi8(const int8_t* __restrict__ S,
                                                   const int8_t* __restrict__ FT,
                                                   bf* __restrict__ outb) {
  constexpr int ABUF = 64 * 128, BBUF = 128 * 128, BUF = ABUF + BBUF;  // 24KB
  __shared__ __align__(16) char sm[3 * BUF];  // 72KB

  const int tid = threadIdx.x;
  const int wave = tid >> 6, lane = tid & 63;
  const int lr = lane & 15, lg = lane >> 4;
  const int wm = wave & 1, wn = (wave >> 1) & 1, ks = wave >> 2;

  const int lin = blockIdx.x;
  const int e = lin & 7, jj = lin >> 3;          // 8 XCDs x 32
  const int bm = e * 8 + (jj >> 2), bn = jj & 3; // 64 m-panels, 4 n-panels
  const int m0 = bm * 64, n0 = bn * 128;

  i32x4 acc[2][4];
#pragma unroll
  for (int i = 0; i < 2; ++i)
#pragma unroll
    for (int f = 0; f < 4; ++f) acc[i][f] = i32x4{0, 0, 0, 0};

  // prologue: K-steps 0 and 1
  stage_rows8<8>(S + (size_t)m0 * M_TOT, M_TOT, sm, wave, lane);
  stage_rows8<16>(FT + (size_t)n0 * M_TOT, M_TOT, sm + ABUF, wave, lane);
  stage_rows8<8>(S + (size_t)m0 * M_TOT + 128, M_TOT, sm + BUF, wave, lane);
  stage_rows8<16>(FT + (size_t)n0 * M_TOT + 128, M_TOT, sm + BUF + ABUF, wave, lane);

  constexpr int NT = M_TOT / 128;  // 32
  for (int t = 0; t < NT; ++t) {
    char* aTc = sm + (t % 3) * BUF;
    char* bTc = aTc + ABUF;
    if (t + 1 < NT) asm volatile("s_waitcnt vmcnt(3)" ::: "memory");
    else            asm volatile("s_waitcnt vmcnt(0)" ::: "memory");
    __builtin_amdgcn_s_barrier();

    if (t + 2 < NT) {
      char* aTn = sm + ((t + 2) % 3) * BUF;
      stage_rows8<8>(S + (size_t)m0 * M_TOT + (t + 2) * 128, M_TOT, aTn, wave, lane);
      stage_rows8<16>(FT + (size_t)n0 * M_TOT + (t + 2) * 128, M_TOT, aTn + ABUF, wave, lane);
    }
    // this wave's K-slot only (ks*64 bytes within the 128B k-step)
    i32x4 a[2], b[4];
#pragma unroll
    for (int i = 0; i < 2; ++i) a[i] = ldf128i(aTc, wm * 32 + i * 16 + lr, ks * 64 + lg * 16);
#pragma unroll
    for (int f = 0; f < 4; ++f) b[f] = ldf128i(bTc, wn * 64 + f * 16 + lr, ks * 64 + lg * 16);
#pragma unroll
    for (int i = 0; i < 2; ++i)
#pragma unroll
      for (int f = 0; f < 4; ++f)
        acc[i][f] = __builtin_amdgcn_mfma_i32_16x16x64_i8(a[i], b[f], acc[i][f], 0, 0, 0);
  }

  // epilogue: pair-reduce the two K-slot partials through LDS
  __syncthreads();
  if (ks == 1) {
    char* dst = sm + (wave - 4) * 8192 + lane * 128;
#pragma unroll
    for (int i = 0; i < 2; ++i)
#pragma unroll
      for (int f = 0; f < 4; ++f) *(i32x4*)(dst + (i * 4 + f) * 16) = acc[i][f];
  }
  __syncthreads();
  if (ks == 0) {
    const char* src = sm + wave * 8192 + lane * 128;
    constexpr float SCALE = 8.0f / 16129.0f;  // (1/127)*(8/127)
#pragma unroll
    for (int i = 0; i < 2; ++i)
#pragma unroll
      for (int f = 0; f < 4; ++f) {
        i32x4 p = *(const i32x4*)(src + (i * 4 + f) * 16);
        int n = n0 + wn * 64 + f * 16 + lr;
#pragma unroll
        for (int r = 0; r < 4; ++r) {
          int m = m0 + wm * 32 + i * 16 + lg * 4 + r;
          outb[(size_t)m * D_EMB + n] = (bf)((float)(acc[i][f][r] + p[r]) * SCALE);
        }
      }
  }
}

// ---------- bf16 GEMM: 8 waves, 3-buffer 1-barrier counted-vmcnt (unchanged R8) ----------
template <int BM, int BN, int OUTMODE>
__global__ __launch_bounds__(512, 1) void k_gemm8(const bf* __restrict__ A, const bf* __restrict__ BT,
                                                  const float* __restrict__ bias, void* __restrict__ out,
                                                  int M, int N, int K) {
  constexpr int WN = BN / 2;
  constexpr int FM = 2, FN = WN / 16;
  constexpr int ABUF = BM * 128, BBUF = BN * 128, BUF = ABUF + BBUF;
  constexpr int LP = BM / 64 + BN / 64;
  static_assert(LP == 3 || LP == 4, "vmcnt literal");
  __shared__ __align__(16) char sm[3 * BUF];

  const int tid = threadIdx.x;
  const int wave = tid >> 6, lane = tid & 63;
  const int lr = lane & 15, lg = lane >> 4;
  const int wm = wave >> 1, wn = wave & 1;

  const int lin = blockIdx.x;
  const int e = lin & 7, jj = lin >> 3;
  const int nbn = N / BN;
  const int bm = e * 4 + jj / nbn, bn = jj % nbn;
  const int m0 = bm * BM, n0 = bn * BN;

  f32x4 acc[FM][FN];
#pragma unroll
  for (int i = 0; i < FM; ++i)
#pragma unroll
    for (int f = 0; f < FN; ++f) acc[i][f] = f32x4{0.f, 0.f, 0.f, 0.f};

  stage_rows8<BM / 8>(A + (size_t)m0 * K, (size_t)K * 2, sm, wave, lane);
  stage_rows8<BN / 8>(BT + (size_t)n0 * K, (size_t)K * 2, sm + ABUF, wave, lane);
  stage_rows8<BM / 8>(A + (size_t)m0 * K + 64, (size_t)K * 2, sm + BUF, wave, lane);
  stage_rows8<BN / 8>(BT + (size_t)n0 * K + 64, (size_t)K * 2, sm + BUF + ABUF, wave, lane);

  const int NT = K / 64;
  for (int t = 0; t < NT; ++t) {
    char* aTc = sm + (t % 3) * BUF;
    char* bTc = aTc + ABUF;
    if (t + 1 < NT) {
      if constexpr (LP == 3) asm volatile("s_waitcnt vmcnt(3)" ::: "memory");
      else                   asm volatile("s_waitcnt vmcnt(4)" ::: "memory");
    } else {
      asm volatile("s_waitcnt vmcnt(0)" ::: "memory");
    }
    __builtin_amdgcn_s_barrier();

    if (t + 2 < NT) {
      char* aTn = sm + ((t + 2) % 3) * BUF;
      stage_rows8<BM / 8>(A + (size_t)m0 * K + (t + 2) * 64, (size_t)K * 2, aTn, wave, lane);
      stage_rows8<BN / 8>(BT + (size_t)n0 * K + (t + 2) * 64, (size_t)K * 2, aTn + ABUF, wave, lane);
    }
#pragma unroll
    for (int ksl = 0; ksl < 2; ++ksl) {
      bf16x8 a[FM], b[FN];
#pragma unroll
      for (int i = 0; i < FM; ++i) a[i] = ldf128(aTc, wm * 32 + i * 16 + lr, (ksl * 32 + lg * 8) * 2);
#pragma unroll
      for (int f = 0; f < FN; ++f) b[f] = ldf128(bTc, wn * WN + f * 16 + lr, (ksl * 32 + lg * 8) * 2);
#pragma unroll
      for (int i = 0; i < FM; ++i)
#pragma unroll
        for (int f = 0; f < FN; ++f)
          acc[i][f] = __builtin_amdgcn_mfma_f32_16x16x32_bf16(a[i], b[f], acc[i][f], 0, 0, 0);
    }
  }

#pragma unroll
  for (int f = 0; f < FN; ++f) {
    int n = n0 + wn * WN + f * 16 + lr;
    float bv = (OUTMODE == 2) ? 0.f : bias[n];
#pragma unroll
    for (int i = 0; i < FM; ++i)
#pragma unroll
      for (int r = 0; r < 4; ++r) {
        int m = m0 + wm * 32 + i * 16 + lg * 4 + r;
        float v = acc[i][f][r] + bv;
        if (OUTMODE == 1) {
          v = v > 0.f ? v : 0.f;
          ((bf*)out)[(size_t)m * N + n] = (bf)v;
        } else {
          ((float*)out)[(size_t)m * N + n] = v;
        }
      }
  }
}

// ---------- workspace layout ----------
constexpr size_t OFF_PHI  = 0;                                        // 256KB
constexpr size_t OFF_FI8  = OFF_PHI + (size_t)M_TOT * 32 * 2;         // 2MB i8 [d][m]
constexpr size_t OFF_OUTB = OFF_FI8 + (size_t)D_EMB * M_TOT;          // 4MB bf16
constexpr size_t OFF_W1T  = OFF_OUTB + (size_t)M_TOT * D_EMB * 2;     // 2MB
constexpr size_t OFF_W2T  = OFF_W1T + (size_t)F_FFN * D_EMB * 2;      // 2MB
constexpr size_t OFF_S    = OFF_W2T + (size_t)D_EMB * F_FFN * 2;      // 16MB i8
constexpr size_t OFF_HB   = OFF_S;  // hb (16MB bf16) reuses S region

extern "C" void kernel_launch(void* const* d_in, const int* in_sizes, int n_in,
                              void* d_out, int out_size, void* d_ws, size_t ws_size,
                              hipStream_t stream) {
  const float* x  = (const float*)d_in[0];
  const float* W1 = (const float*)d_in[1];
  const float* b1 = (const float*)d_in[2];
  const float* W2 = (const float*)d_in[3];
  const float* b2 = (const float*)d_in[4];
  float* y = (float*)d_out;
  char* ws = (char*)d_ws;

  bf* phib    = (bf*)(ws + OFF_PHI);
  int8_t* fi8 = (int8_t*)(ws + OFF_FI8);
  bf* outb    = (bf*)(ws + OFF_OUTB);
  bf* w1T     = (bf*)(ws + OFF_W1T);
  bf* w2T     = (bf*)(ws + OFF_W2T);
  int8_t* S   = (int8_t*)(ws + OFF_S);
  bf* hb      = (bf*)(ws + OFF_HB);

  k_prep<<<dim3(NT_FT + NT_W1 + NT_W2 + NT_PHI), 256, 0, stream>>>(x, W1, W2, fi8, w1T, w2T, phib);

  k_sgen<<<dim3(1024), 256, 0, stream>>>(phib, S);
  k_gemmi8<<<dim3(256), 512, 0, stream>>>(S, fi8, outb);

  k_gemm8<128, 128, 1><<<dim3(512), 512, 0, stream>>>(outb, w1T, b1, (void*)hb, M_TOT, F_FFN, D_EMB);
  k_gemm8<128, 64, 0><<<dim3(256), 512, 0, stream>>>(hb, w2T, b2, (void*)y, M_TOT, D_EMB, F_FFN);
}

// Round 10
// 68.124 us; speedup vs baseline: 1.9240x; 1.0004x over previous
//
#include <hip/hip_runtime.h>
#include <hip/hip_bf16.h>
#include <stdint.h>

using bf = __bf16;
typedef __attribute__((ext_vector_type(8))) __bf16 bf16x8;
typedef __attribute__((ext_vector_type(4))) float f32x4;
typedef __attribute__((ext_vector_type(4))) int i32x4;

#define M_TOT 4096
#define D_EMB 512
#define F_FFN 2048

// ---------- async global->LDS, 16B per lane ----------
__device__ __forceinline__ void gload_lds16(const void* g, void* l) {
  __builtin_amdgcn_global_load_lds(
      (const __attribute__((address_space(1))) uint32_t*)g,
      (__attribute__((address_space(3))) uint32_t*)l, 16, 0, 0);
}

// ---------- 128B-row swizzled tiles ----------
__device__ __forceinline__ int swz128(int row, int b) {
  return row * 128 + (b ^ ((row & 7) << 4));
}
__device__ __forceinline__ bf16x8 ldf128(const char* base, int row, int b) {
  return *(const bf16x8*)(base + swz128(row, b));
}
__device__ __forceinline__ i32x4 ldf128i(const char* base, int row, int b) {
  return *(const i32x4*)(base + swz128(row, b));
}
// 8-wave stager: CHUNKS x 1KB; linear LDS dest + inverse-swizzled source
template <int CHUNKS>
__device__ __forceinline__ void stage_rows8(const void* gsrc, size_t ld_bytes, char* lbase,
                                            int wave, int lane) {
  const int rsub = lane >> 3, csub = lane & 7;
  const int sc = csub ^ rsub;
#pragma unroll
  for (int i = 0; i < CHUNKS / 8; ++i) {
    int chunk = wave + i * 8;
    int row = chunk * 8 + rsub;
    gload_lds16((const char*)gsrc + (size_t)row * ld_bytes + sc * 16, lbase + chunk * 1024);
  }
}
// 4-wave stager
template <int CHUNKS>
__device__ __forceinline__ void stage_rows4(const void* gsrc, size_t ld_bytes, char* lbase,
                                            int wave, int lane) {
  const int rsub = lane >> 3, csub = lane & 7;
  const int sc = csub ^ rsub;
#pragma unroll
  for (int i = 0; i < CHUNKS / 4; ++i) {
    int chunk = wave + i * 4;
    int row = chunk * 8 + rsub;
    gload_lds16((const char*)gsrc + (size_t)row * ld_bytes + sc * 16, lbase + chunk * 1024);
  }
}

__device__ __forceinline__ int quant_i8(float x, float s) {
  float v = x * s;
  v = fminf(127.f, fmaxf(-127.f, v));
  return (int)rintf(v);
}

// ---------- merged prep + sgen ----------
// bid < 1024          : S-gen block (computes own phi in LDS)
// next 2048           : x -> fi8^T (i8, scale 127/8)
// next 1024           : W1 -> w1T bf16
// next 1024           : W2 -> w2T bf16
#define NB_SGEN 1024
#define NT_FT   2048
#define NT_W1   1024
#define NT_W2   1024

__global__ __launch_bounds__(256) void k_prep(const float* __restrict__ x,
                                              const float* __restrict__ W1,
                                              const float* __restrict__ W2,
                                              int8_t* __restrict__ fi8, bf* __restrict__ w1T,
                                              bf* __restrict__ w2T, int8_t* __restrict__ S) {
  __shared__ __align__(16) char smem[32768];
  const int bid = blockIdx.x, tid = threadIdx.x;

  if (bid < NB_SGEN) {
    // ---- S tile: rows m0..m0+127, cols j0..j0+127, i8, written transposed ----
    char* phiL = smem;          // [256][32] bf16 (rows 0-127: M-set, 128-255: J-set)
    char* st = smem + 16384;    // S^T tile [128 j][128 m] i8, swizzled
    const int m0 = (bid & 31) * 128;
    const int j0 = (bid >> 5) * 128;
    // per-thread phi row
    {
      int g = (tid < 128) ? (m0 + tid) : (j0 + tid - 128);
      float c[4], s[4];
#pragma unroll
      for (int k = 0; k < 4; ++k) {
        float f = x[(size_t)g * D_EMB + k] * 0.5f;
        sincosf(f, &s[k], &c[k]);
      }
      bf* row = (bf*)(phiL + tid * 64);
#pragma unroll
      for (int m = 0; m < 16; ++m) {
        float p = 1.0f;
#pragma unroll
        for (int k = 0; k < 4; ++k) p *= ((m >> k) & 1) ? s[k] : c[k];
        row[m] = (bf)p;
      }
#pragma unroll
      for (int m = 16; m < 32; ++m) row[m] = (bf)0.0f;
    }
    __syncthreads();

    const int wave = tid >> 6, lane = tid & 63;
    const int lr = lane & 15, lg = lane >> 4;
    const bf16x8 a0 = *(const bf16x8*)(phiL + (wave * 32 + lr) * 64 + lg * 16);
    const bf16x8 a1 = *(const bf16x8*)(phiL + (wave * 32 + 16 + lr) * 64 + lg * 16);

    const int mb0 = wave * 32 + lg * 4;
    const int key = (lr & 7) << 4;
#pragma unroll
    for (int jf = 0; jf < 8; ++jf) {
      bf16x8 b = *(const bf16x8*)(phiL + (128 + jf * 16 + lr) * 64 + lg * 16);
      f32x4 s0 = __builtin_amdgcn_mfma_f32_16x16x32_bf16(a0, b, f32x4{0.f, 0.f, 0.f, 0.f}, 0, 0, 0);
      f32x4 s1 = __builtin_amdgcn_mfma_f32_16x16x32_bf16(a1, b, f32x4{0.f, 0.f, 0.f, 0.f}, 0, 0, 0);
      uint32_t w0 = 0, w1 = 0;
#pragma unroll
      for (int r = 0; r < 4; ++r) {
        uint32_t q0 = (uint32_t)min(127, (int)rintf(fabsf(s0[r]) * 127.f));
        uint32_t q1 = (uint32_t)min(127, (int)rintf(fabsf(s1[r]) * 127.f));
        w0 |= q0 << (8 * r);
        w1 |= q1 << (8 * r);
      }
      int jrow = jf * 16 + lr;
      *(uint32_t*)(st + jrow * 128 + (mb0 ^ key)) = w0;
      *(uint32_t*)(st + jrow * 128 + ((mb0 + 16) ^ key)) = w1;
    }
    __syncthreads();
#pragma unroll
    for (int i = 0; i < 4; ++i) {
      int idx = tid + i * 256;
      int jrow = idx >> 3, seg = idx & 7;
      i32x4 v = *(const i32x4*)(st + jrow * 128 + ((seg * 16) ^ ((jrow & 7) << 4)));
      *(i32x4*)(S + (size_t)(j0 + jrow) * M_TOT + m0 + seg * 16) = v;
    }
    return;
  }

  float(*tile)[33] = (float(*)[33])smem;
  const int tx = tid & 31, ty = tid >> 5;
  if (bid < NB_SGEN + NT_FT) {
    int b2 = bid - NB_SGEN;
    int c0 = (b2 % (D_EMB / 32)) * 32, r0 = (b2 / (D_EMB / 32)) * 32;
#pragma unroll
    for (int i = 0; i < 32; i += 8)
      tile[ty + i][tx] = x[(size_t)(r0 + ty + i) * D_EMB + c0 + tx];
    __syncthreads();
#pragma unroll
    for (int i = 0; i < 32; i += 8)
      fi8[(size_t)(c0 + ty + i) * M_TOT + r0 + tx] = (int8_t)quant_i8(tile[tx][ty + i], 15.875f);
  } else if (bid < NB_SGEN + NT_FT + NT_W1) {
    int b2 = bid - NB_SGEN - NT_FT;
    int c0 = (b2 % (F_FFN / 32)) * 32, r0 = (b2 / (F_FFN / 32)) * 32;
#pragma unroll
    for (int i = 0; i < 32; i += 8)
      tile[ty + i][tx] = W1[(size_t)(r0 + ty + i) * F_FFN + c0 + tx];
    __syncthreads();
#pragma unroll
    for (int i = 0; i < 32; i += 8)
      w1T[(size_t)(c0 + ty + i) * D_EMB + r0 + tx] = (bf)tile[tx][ty + i];
  } else {
    int b2 = bid - NB_SGEN - NT_FT - NT_W1;
    int c0 = (b2 % (D_EMB / 32)) * 32, r0 = (b2 / (D_EMB / 32)) * 32;
#pragma unroll
    for (int i = 0; i < 32; i += 8)
      tile[ty + i][tx] = W2[(size_t)(r0 + ty + i) * D_EMB + c0 + tx];
    __syncthreads();
#pragma unroll
    for (int i = 0; i < 32; i += 8)
      w2T[(size_t)(c0 + ty + i) * F_FFN + r0 + tx] = (bf)tile[tx][ty + i];
  }
}

// ---------- i8 GEMM: out = (S/127) @ (flat*127/8)^T * scale (unchanged R9) ----------
__global__ __launch_bounds__(512, 1) void k_gemmi8(const int8_t* __restrict__ S,
                                                   const int8_t* __restrict__ FT,
                                                   bf* __restrict__ outb) {
  constexpr int ABUF = 64 * 128, BBUF = 128 * 128, BUF = ABUF + BBUF;
  __shared__ __align__(16) char sm[3 * BUF];

  const int tid = threadIdx.x;
  const int wave = tid >> 6, lane = tid & 63;
  const int lr = lane & 15, lg = lane >> 4;
  const int wm = wave & 1, wn = (wave >> 1) & 1, ks = wave >> 2;

  const int lin = blockIdx.x;
  const int e = lin & 7, jj = lin >> 3;
  const int bm = e * 8 + (jj >> 2), bn = jj & 3;
  const int m0 = bm * 64, n0 = bn * 128;

  i32x4 acc[2][4];
#pragma unroll
  for (int i = 0; i < 2; ++i)
#pragma unroll
    for (int f = 0; f < 4; ++f) acc[i][f] = i32x4{0, 0, 0, 0};

  stage_rows8<8>(S + (size_t)m0 * M_TOT, M_TOT, sm, wave, lane);
  stage_rows8<16>(FT + (size_t)n0 * M_TOT, M_TOT, sm + ABUF, wave, lane);
  stage_rows8<8>(S + (size_t)m0 * M_TOT + 128, M_TOT, sm + BUF, wave, lane);
  stage_rows8<16>(FT + (size_t)n0 * M_TOT + 128, M_TOT, sm + BUF + ABUF, wave, lane);

  constexpr int NT = M_TOT / 128;
  for (int t = 0; t < NT; ++t) {
    char* aTc = sm + (t % 3) * BUF;
    char* bTc = aTc + ABUF;
    if (t + 1 < NT) asm volatile("s_waitcnt vmcnt(3)" ::: "memory");
    else            asm volatile("s_waitcnt vmcnt(0)" ::: "memory");
    __builtin_amdgcn_s_barrier();

    if (t + 2 < NT) {
      char* aTn = sm + ((t + 2) % 3) * BUF;
      stage_rows8<8>(S + (size_t)m0 * M_TOT + (t + 2) * 128, M_TOT, aTn, wave, lane);
      stage_rows8<16>(FT + (size_t)n0 * M_TOT + (t + 2) * 128, M_TOT, aTn + ABUF, wave, lane);
    }
    i32x4 a[2], b[4];
#pragma unroll
    for (int i = 0; i < 2; ++i) a[i] = ldf128i(aTc, wm * 32 + i * 16 + lr, ks * 64 + lg * 16);
#pragma unroll
    for (int f = 0; f < 4; ++f) b[f] = ldf128i(bTc, wn * 64 + f * 16 + lr, ks * 64 + lg * 16);
#pragma unroll
    for (int i = 0; i < 2; ++i)
#pragma unroll
      for (int f = 0; f < 4; ++f)
        acc[i][f] = __builtin_amdgcn_mfma_i32_16x16x64_i8(a[i], b[f], acc[i][f], 0, 0, 0);
  }

  __syncthreads();
  if (ks == 1) {
    char* dst = sm + (wave - 4) * 8192 + lane * 128;
#pragma unroll
    for (int i = 0; i < 2; ++i)
#pragma unroll
      for (int f = 0; f < 4; ++f) *(i32x4*)(dst + (i * 4 + f) * 16) = acc[i][f];
  }
  __syncthreads();
  if (ks == 0) {
    const char* src = sm + wave * 8192 + lane * 128;
    constexpr float SCALE = 8.0f / 16129.0f;
#pragma unroll
    for (int i = 0; i < 2; ++i)
#pragma unroll
      for (int f = 0; f < 4; ++f) {
        i32x4 p = *(const i32x4*)(src + (i * 4 + f) * 16);
        int n = n0 + wn * 64 + f * 16 + lr;
#pragma unroll
        for (int r = 0; r < 4; ++r) {
          int m = m0 + wm * 32 + i * 16 + lg * 4 + r;
          outb[(size_t)m * D_EMB + n] = (bf)((float)(acc[i][f][r] + p[r]) * SCALE);
        }
      }
  }
}

// ---------- bf16 GEMM, 4 waves, BM128 x BN64, 3-buffer counted-vmcnt ----------
// wave grid 2m x 2n, wave tile 64x32. Grid = 8 XCD x 4 bm x (N/64) bn.
__global__ __launch_bounds__(256, 2) void k_gemm4(const bf* __restrict__ A, const bf* __restrict__ BT,
                                                  const float* __restrict__ bias, bf* __restrict__ out,
                                                  int M, int N, int K) {
  constexpr int BM = 128, BN = 64;
  constexpr int ABUF = BM * 128, BBUF = BN * 128, BUF = ABUF + BBUF;  // 24KB
  __shared__ __align__(16) char sm[3 * BUF];  // 72KB -> 2 blocks/CU

  const int tid = threadIdx.x;
  const int wave = tid >> 6, lane = tid & 63;
  const int lr = lane & 15, lg = lane >> 4;
  const int wm = wave >> 1, wn = wave & 1;

  const int lin = blockIdx.x;
  const int e = lin & 7, jj = lin >> 3;
  const int bm = e * 4 + (jj & 3), bn = jj >> 2;
  const int m0 = bm * BM, n0 = bn * BN;

  f32x4 acc[4][2];
#pragma unroll
  for (int i = 0; i < 4; ++i)
#pragma unroll
    for (int f = 0; f < 2; ++f) acc[i][f] = f32x4{0.f, 0.f, 0.f, 0.f};

  stage_rows4<16>(A + (size_t)m0 * K, (size_t)K * 2, sm, wave, lane);
  stage_rows4<8>(BT + (size_t)n0 * K, (size_t)K * 2, sm + ABUF, wave, lane);
  stage_rows4<16>(A + (size_t)m0 * K + 64, (size_t)K * 2, sm + BUF, wave, lane);
  stage_rows4<8>(BT + (size_t)n0 * K + 64, (size_t)K * 2, sm + BUF + ABUF, wave, lane);

  const int NT = K / 64;
  for (int t = 0; t < NT; ++t) {
    char* aTc = sm + (t % 3) * BUF;
    char* bTc = aTc + ABUF;
    if (t + 1 < NT) asm volatile("s_waitcnt vmcnt(6)" ::: "memory");
    else            asm volatile("s_waitcnt vmcnt(0)" ::: "memory");
    __builtin_amdgcn_s_barrier();

    if (t + 2 < NT) {
      char* aTn = sm + ((t + 2) % 3) * BUF;
      stage_rows4<16>(A + (size_t)m0 * K + (t + 2) * 64, (size_t)K * 2, aTn, wave, lane);
      stage_rows4<8>(BT + (size_t)n0 * K + (t + 2) * 64, (size_t)K * 2, aTn + ABUF, wave, lane);
    }
#pragma unroll
    for (int ksl = 0; ksl < 2; ++ksl) {
      bf16x8 a[4], b[2];
#pragma unroll
      for (int i = 0; i < 4; ++i) a[i] = ldf128(aTc, wm * 64 + i * 16 + lr, (ksl * 32 + lg * 8) * 2);
#pragma unroll
      for (int f = 0; f < 2; ++f) b[f] = ldf128(bTc, wn * 32 + f * 16 + lr, (ksl * 32 + lg * 8) * 2);
#pragma unroll
      for (int i = 0; i < 4; ++i)
#pragma unroll
        for (int f = 0; f < 2; ++f)
          acc[i][f] = __builtin_amdgcn_mfma_f32_16x16x32_bf16(a[i], b[f], acc[i][f], 0, 0, 0);
    }
  }

#pragma unroll
  for (int f = 0; f < 2; ++f) {
    int n = n0 + wn * 32 + f * 16 + lr;
    float bv = bias[n];
#pragma unroll
    for (int i = 0; i < 4; ++i)
#pragma unroll
      for (int r = 0; r < 4; ++r) {
        int m = m0 + wm * 64 + i * 16 + lg * 4 + r;
        float v = acc[i][f][r] + bv;
        v = v > 0.f ? v : 0.f;
        out[(size_t)m * N + n] = (bf)v;
      }
  }
}

// ---------- bf16 GEMM: 8 waves, 3-buffer counted-vmcnt (R8, gemm2 only) ----------
template <int BM, int BN, int OUTMODE>
__global__ __launch_bounds__(512, 1) void k_gemm8(const bf* __restrict__ A, const bf* __restrict__ BT,
                                                  const float* __restrict__ bias, void* __restrict__ out,
                                                  int M, int N, int K) {
  constexpr int WN = BN / 2;
  constexpr int FM = 2, FN = WN / 16;
  constexpr int ABUF = BM * 128, BBUF = BN * 128, BUF = ABUF + BBUF;
  constexpr int LP = BM / 64 + BN / 64;
  static_assert(LP == 3 || LP == 4, "vmcnt literal");
  __shared__ __align__(16) char sm[3 * BUF];

  const int tid = threadIdx.x;
  const int wave = tid >> 6, lane = tid & 63;
  const int lr = lane & 15, lg = lane >> 4;
  const int wm = wave >> 1, wn = wave & 1;

  const int lin = blockIdx.x;
  const int e = lin & 7, jj = lin >> 3;
  const int nbn = N / BN;
  const int bm = e * 4 + jj / nbn, bn = jj % nbn;
  const int m0 = bm * BM, n0 = bn * BN;

  f32x4 acc[FM][FN];
#pragma unroll
  for (int i = 0; i < FM; ++i)
#pragma unroll
    for (int f = 0; f < FN; ++f) acc[i][f] = f32x4{0.f, 0.f, 0.f, 0.f};

  stage_rows8<BM / 8>(A + (size_t)m0 * K, (size_t)K * 2, sm, wave, lane);
  stage_rows8<BN / 8>(BT + (size_t)n0 * K, (size_t)K * 2, sm + ABUF, wave, lane);
  stage_rows8<BM / 8>(A + (size_t)m0 * K + 64, (size_t)K * 2, sm + BUF, wave, lane);
  stage_rows8<BN / 8>(BT + (size_t)n0 * K + 64, (size_t)K * 2, sm + BUF + ABUF, wave, lane);

  const int NT = K / 64;
  for (int t = 0; t < NT; ++t) {
    char* aTc = sm + (t % 3) * BUF;
    char* bTc = aTc + ABUF;
    if (t + 1 < NT) {
      if constexpr (LP == 3) asm volatile("s_waitcnt vmcnt(3)" ::: "memory");
      else                   asm volatile("s_waitcnt vmcnt(4)" ::: "memory");
    } else {
      asm volatile("s_waitcnt vmcnt(0)" ::: "memory");
    }
    __builtin_amdgcn_s_barrier();

    if (t + 2 < NT) {
      char* aTn = sm + ((t + 2) % 3) * BUF;
      stage_rows8<BM / 8>(A + (size_t)m0 * K + (t + 2) * 64, (size_t)K * 2, aTn, wave, lane);
      stage_rows8<BN / 8>(BT + (size_t)n0 * K + (t + 2) * 64, (size_t)K * 2, aTn + ABUF, wave, lane);
    }
#pragma unroll
    for (int ksl = 0; ksl < 2; ++ksl) {
      bf16x8 a[FM], b[FN];
#pragma unroll
      for (int i = 0; i < FM; ++i) a[i] = ldf128(aTc, wm * 32 + i * 16 + lr, (ksl * 32 + lg * 8) * 2);
#pragma unroll
      for (int f = 0; f < FN; ++f) b[f] = ldf128(bTc, wn * WN + f * 16 + lr, (ksl * 32 + lg * 8) * 2);
#pragma unroll
      for (int i = 0; i < FM; ++i)
#pragma unroll
        for (int f = 0; f < FN; ++f)
          acc[i][f] = __builtin_amdgcn_mfma_f32_16x16x32_bf16(a[i], b[f], acc[i][f], 0, 0, 0);
    }
  }

#pragma unroll
  for (int f = 0; f < FN; ++f) {
    int n = n0 + wn * WN + f * 16 + lr;
    float bv = (OUTMODE == 2) ? 0.f : bias[n];
#pragma unroll
    for (int i = 0; i < FM; ++i)
#pragma unroll
      for (int r = 0; r < 4; ++r) {
        int m = m0 + wm * 32 + i * 16 + lg * 4 + r;
        float v = acc[i][f][r] + bv;
        if (OUTMODE == 1) {
          v = v > 0.f ? v : 0.f;
          ((bf*)out)[(size_t)m * N + n] = (bf)v;
        } else {
          ((float*)out)[(size_t)m * N + n] = v;
        }
      }
  }
}

// ---------- workspace layout ----------
constexpr size_t OFF_FI8  = 0;                                     // 2MB i8 [d][m]
constexpr size_t OFF_OUTB = OFF_FI8 + (size_t)D_EMB * M_TOT;       // 4MB bf16
constexpr size_t OFF_W1T  = OFF_OUTB + (size_t)M_TOT * D_EMB * 2;  // 2MB
constexpr size_t OFF_W2T  = OFF_W1T + (size_t)F_FFN * D_EMB * 2;   // 2MB
constexpr size_t OFF_S    = OFF_W2T + (size_t)D_EMB * F_FFN * 2;   // 16MB i8
constexpr size_t OFF_HB   = OFF_S;  // hb (16MB bf16) reuses S region

extern "C" void kernel_launch(void* const* d_in, const int* in_sizes, int n_in,
                              void* d_out, int out_size, void* d_ws, size_t ws_size,
                              hipStream_t stream) {
  const float* x  = (const float*)d_in[0];
  const float* W1 = (const float*)d_in[1];
  const float* b1 = (const float*)d_in[2];
  const float* W2 = (const float*)d_in[3];
  const float* b2 = (const float*)d_in[4];
  float* y = (float*)d_out;
  char* ws = (char*)d_ws;

  int8_t* fi8 = (int8_t*)(ws + OFF_FI8);
  bf* outb    = (bf*)(ws + OFF_OUTB);
  bf* w1T     = (bf*)(ws + OFF_W1T);
  bf* w2T     = (bf*)(ws + OFF_W2T);
  int8_t* S   = (int8_t*)(ws + OFF_S);
  bf* hb      = (bf*)(ws + OFF_HB);

  // merged prep + sgen (sgen blocks first; they're the heaviest)
  k_prep<<<dim3(NB_SGEN + NT_FT + NT_W1 + NT_W2), 256, 0, stream>>>(x, W1, W2, fi8, w1T, w2T, S);

  k_gemmi8<<<dim3(256), 512, 0, stream>>>(S, fi8, outb);

  // FFN
  k_gemm4<<<dim3(1024), 256, 0, stream>>>(outb, w1T, b1, hb, M_TOT, F_FFN, D_EMB);
  k_gemm8<128, 64, 0><<<dim3(256), 512, 0, stream>>>(hb, w2T, b2, (void*)y, M_TOT, D_EMB, F_FFN);
}